// Round 10
// baseline (127.940 us; speedup 1.0000x reference)
//
#include <hip/hip_runtime.h>

namespace {

constexpr int T_LEN = 512;
constexpr int XS    = 516;   // padded floats per x-row in LDS

typedef _Float16 half8  __attribute__((ext_vector_type(8)));
typedef float    f32x4v __attribute__((ext_vector_type(4)));
typedef unsigned uint2v __attribute__((ext_vector_type(2)));
typedef unsigned uint4v __attribute__((ext_vector_type(4)));

#define MFMA32(a, b, c) __builtin_amdgcn_mfma_f32_16x16x32_f16((a), (b), (c), 0, 0, 0)

// tanh(y) = 1 - 2/(2^(SCL*y)+1) with SCL = 2*log2(e) pre-folded into weights.
constexpr float SCL = 2.8853900817779268f;

__device__ __forceinline__ float exp2_fast(float x) {
#if __has_builtin(__builtin_amdgcn_exp2f)
    return __builtin_amdgcn_exp2f(x);
#else
    return exp2f(x);
#endif
}

// Load an fp16 A-fragment from a row-major 64x64 fp32 matrix, scaled.
__device__ __forceinline__ half8 load_frag(const float* __restrict__ W,
                                           int row, int k0, float s) {
    const float* p = W + row * 64 + k0;
    f32x4v lo = *reinterpret_cast<const f32x4v*>(p);
    f32x4v hi = *reinterpret_cast<const f32x4v*>(p + 4);
    uint4v u;
    u.x = __builtin_bit_cast(unsigned, __builtin_amdgcn_cvt_pkrtz(lo.x * s, lo.y * s));
    u.y = __builtin_bit_cast(unsigned, __builtin_amdgcn_cvt_pkrtz(lo.z * s, lo.w * s));
    u.z = __builtin_bit_cast(unsigned, __builtin_amdgcn_cvt_pkrtz(hi.x * s, hi.y * s));
    u.w = __builtin_bit_cast(unsigned, __builtin_amdgcn_cvt_pkrtz(hi.z * s, hi.w * s));
    return __builtin_bit_cast(half8, u);
}

// Single-group tanh for peel/epilogue (a holds SCL*preact, log2-domain).
__device__ __forceinline__ void tanh4(f32x4v &a) {
#pragma unroll
    for (int q = 0; q < 4; ++q) {
        float e = exp2_fast(a[q]);
        a[q] = 1.0f - 2.0f * __builtin_amdgcn_rcpf(e + 1.0f);
    }
}

// Swizzled halves-offset into a [16][64]-half exchange buffer.
__device__ __forceinline__ int swz_off(int b, int ro) {
    const int chunk = ro >> 3;
    const int within = ro & 7;
    return (b << 6) + ((chunk ^ (b & 7)) << 3) + within;
}

__global__ __launch_bounds__(256, 2)
void rnn_stag_kernel(const float* __restrict__ x,
                     const float* __restrict__ Wih0,
                     const float* __restrict__ Whh0,
                     const float* __restrict__ bih0,
                     const float* __restrict__ bhh0,
                     const float* __restrict__ Wih1,
                     const float* __restrict__ Whh1,
                     const float* __restrict__ bih1,
                     const float* __restrict__ bhh1,
                     const float* __restrict__ fc1W,
                     const float* __restrict__ fc1b,
                     const float* __restrict__ fc2W,
                     const float* __restrict__ fc2b,
                     float* __restrict__ out)
{
    const int tid    = threadIdx.x;        // 256 threads = 4 waves
    const int wv     = tid >> 6;           // wave owns hidden rows 16wv..16wv+15
    const int lane   = tid & 63;
    const int g      = lane >> 4;
    const int b16    = lane & 15;          // batch within 16-batch tile
    const int batch0 = blockIdx.x * 16;

    __shared__ float    sx[16 * XS];       // whole x tile, staged once
    __shared__ _Float16 sh1[2][16 * 64];   // h1 exchange, ping-pong, swizzled
    __shared__ _Float16 sh2[2][16 * 64];   // h2 exchange
    __shared__ float    pf[4][16];         // fc2 partials

    // ---- stage x[batch0..+15][0..511] into LDS (coalesced f32x4) ----
    {
        const float* gx = x + (size_t)batch0 * T_LEN;
#pragma unroll
        for (int c = 0; c < 8; ++c) {
            int idx = tid + c * 256;            // float4 index 0..2047
            int r = idx >> 7, c4 = idx & 127;   // 128 float4 per row
            f32x4v v = *reinterpret_cast<const f32x4v*>(gx + r * T_LEN + c4 * 4);
            *reinterpret_cast<f32x4v*>(&sx[r * XS + c4 * 4]) = v;
        }
    }

    // ---- per-wave persistent weights (SCL folds tanh's 2y and log2e) ----
    const int row = 16 * wv + b16;
    const int ro  = 16 * wv + 4 * g;

    const half8 WA0_0 = load_frag(Whh0, row,      8 * g, SCL);
    const half8 WA0_1 = load_frag(Whh0, row, 32 + 8 * g, SCL);
    const half8 WI1_0 = load_frag(Wih1, row,      8 * g, SCL);
    const half8 WI1_1 = load_frag(Wih1, row, 32 + 8 * g, SCL);
    const half8 WH1_0 = load_frag(Whh1, row,      8 * g, SCL);
    const half8 WH1_1 = load_frag(Whh1, row, 32 + 8 * g, SCL);

    f32x4v bb0, bb1, wx2;
#pragma unroll
    for (int q = 0; q < 4; ++q) {
        const int o = 16 * wv + 4 * g + q;
        bb0[q] = SCL * (bih0[o] + bhh0[o]);
        bb1[q] = SCL * (bih1[o] + bhh1[o]);
        wx2[q] = SCL * Wih0[o];
    }

    // step-invariant LDS offsets (halves)
    const int wr_off = swz_off(b16, ro);
    const int rd_b0  = swz_off(b16, 8 * g);
    const int rd_b1  = swz_off(b16, 32 + 8 * g);

    auto publish = [&](_Float16* base, const f32x4v& a) {
        uint2v p;
        p.x = __builtin_bit_cast(unsigned, __builtin_amdgcn_cvt_pkrtz(a[0], a[1]));
        p.y = __builtin_bit_cast(unsigned, __builtin_amdgcn_cvt_pkrtz(a[2], a[3]));
        *reinterpret_cast<uint2v*>(base + wr_off) = p;
    };

    half8 Bh1_0, Bh1_1, Bh2_0, Bh2_1;

    __syncthreads();                       // x staged

    float xt = sx[b16 * XS + 0];
    float xn = sx[b16 * XS + 1];

    // ---- peel k=0: h1(0) = tanh(wx*x0 + b0); h2(-1) = 0 ----
    {
        f32x4v a0 = wx2 * xt + bb0;
        tanh4(a0);
        publish(sh1[0], a0);
        *reinterpret_cast<uint2v*>(&sh2[0][0] + wr_off) = uint2v{0, 0};
        __syncthreads();
        Bh2_0 = *reinterpret_cast<const half8*>(&sh2[0][0] + rd_b0);
        Bh2_1 = *reinterpret_cast<const half8*>(&sh2[0][0] + rd_b1);
        Bh1_0 = *reinterpret_cast<const half8*>(&sh1[0][0] + rd_b0);
        Bh1_1 = *reinterpret_cast<const half8*>(&sh1[0][0] + rd_b1);
        xt = xn; xn = sx[b16 * XS + 2];
    }

    f32x4v c0 = wx2 * xt + bb0;            // u0's C-operand, one step ahead

    // ---- main: iter k computes h1(k) and h2(k-1); one barrier per step ----
#pragma unroll 2
    for (int k = 1; k < T_LEN; ++k) {
        const int s = k & 1;
        const float xf = sx[b16 * XS + k + 2];   // prefetch (pad covers k=511)

        f32x4v zz = {};
        // a0-path first (two parallel 1-chains) so a0 exits MFMA pipe earliest
        f32x4v u0 = MFMA32(WA0_0, Bh1_0, c0);
        f32x4v v0 = MFMA32(WA0_1, Bh1_1, zz);
        f32x4v v1 = MFMA32(WH1_0, Bh2_0, bb1);   // layer1: two parallel 2-chains
        f32x4v u1 = MFMA32(WI1_0, Bh1_0, zz);
        v1 = MFMA32(WH1_1, Bh2_1, v1);
        u1 = MFMA32(WI1_1, Bh1_1, u1);

        // staggered tanh pipeline: exp2 bursts, finish+publish h1 early
        f32x4v a0 = u0 + v0;
        f32x4v e0;
#pragma unroll
        for (int q = 0; q < 4; ++q) e0[q] = exp2_fast(a0[q]);
        f32x4v a1 = u1 + v1;
        f32x4v e1;
#pragma unroll
        for (int q = 0; q < 4; ++q) e1[q] = exp2_fast(a1[q]);

        e0 += 1.0f;
#pragma unroll
        for (int q = 0; q < 4; ++q)
            a0[q] = 1.0f - 2.0f * __builtin_amdgcn_rcpf(e0[q]);
        publish(sh1[s], a0);                     // h1(k): write drains early

        e1 += 1.0f;
#pragma unroll
        for (int q = 0; q < 4; ++q)
            a1[q] = 1.0f - 2.0f * __builtin_amdgcn_rcpf(e1[q]);
        publish(sh2[s], a1);                     // h2(k-1)

        c0 = wx2 * xn + bb0;                     // C-operand for step k+1

        __syncthreads();
        Bh2_0 = *reinterpret_cast<const half8*>(&sh2[s][0] + rd_b0);
        Bh2_1 = *reinterpret_cast<const half8*>(&sh2[s][0] + rd_b1);
        Bh1_0 = *reinterpret_cast<const half8*>(&sh1[s][0] + rd_b0);
        Bh1_1 = *reinterpret_cast<const half8*>(&sh1[s][0] + rd_b1);
        xt = xn; xn = xf;
    }

    // ---- epilogue: h2(511) from h1(511), h2(510) ----
    {
        f32x4v zz = {};
        f32x4v v1 = MFMA32(WH1_0, Bh2_0, bb1);
        f32x4v u1 = MFMA32(WI1_0, Bh1_0, zz);
        v1 = MFMA32(WH1_1, Bh2_1, v1);
        u1 = MFMA32(WI1_1, Bh1_1, u1);
        f32x4v a1 = u1 + v1;
        tanh4(a1);
        publish(sh2[0], a1);
        __syncthreads();
        Bh2_0 = *reinterpret_cast<const half8*>(&sh2[0][0] + rd_b0);
        Bh2_1 = *reinterpret_cast<const half8*>(&sh2[0][0] + rd_b1);
    }

    // ---- fc1 + relu + fc2 ----
    {
        const half8 F0 = load_frag(fc1W, row,      8 * g, 1.0f);
        const half8 F1 = load_frag(fc1W, row, 32 + 8 * g, 1.0f);
        f32x4v zf;
#pragma unroll
        for (int q = 0; q < 4; ++q) zf[q] = fc1b[16 * wv + 4 * g + q];
        zf = MFMA32(F0, Bh2_0, zf);
        zf = MFMA32(F1, Bh2_1, zf);

        float pacc = 0.0f;
#pragma unroll
        for (int q = 0; q < 4; ++q)
            pacc += fmaxf(zf[q], 0.0f) * fc2W[16 * wv + 4 * g + q];
        pacc += __shfl_xor(pacc, 16);
        pacc += __shfl_xor(pacc, 32);
        if (lane < 16) pf[wv][lane] = pacc;
    }
    __syncthreads();
    if (tid < 16)
        out[batch0 + tid] = pf[0][tid] + pf[1][tid] + pf[2][tid] + pf[3][tid]
                          + fc2b[0];
}

} // namespace

extern "C" void kernel_launch(void* const* d_in, const int* in_sizes, int n_in,
                              void* d_out, int out_size, void* d_ws, size_t ws_size,
                              hipStream_t stream) {
    (void)n_in; (void)out_size; (void)d_ws; (void)ws_size;
    const float* x    = (const float*)d_in[0];
    const float* Wih0 = (const float*)d_in[1];
    const float* Whh0 = (const float*)d_in[2];
    const float* bih0 = (const float*)d_in[3];
    const float* bhh0 = (const float*)d_in[4];
    const float* Wih1 = (const float*)d_in[5];
    const float* Whh1 = (const float*)d_in[6];
    const float* bih1 = (const float*)d_in[7];
    const float* bhh1 = (const float*)d_in[8];
    const float* fc1W = (const float*)d_in[9];
    const float* fc1b = (const float*)d_in[10];
    const float* fc2W = (const float*)d_in[11];
    const float* fc2b = (const float*)d_in[12];
    float* out = (float*)d_out;

    const int B = in_sizes[0] / T_LEN;      // 4096
    dim3 grid(B / 16), block(256);
    rnn_stag_kernel<<<grid, block, 0, stream>>>(
        x, Wih0, Whh0, bih0, bhh0, Wih1, Whh1, bih1, bhh1,
        fc1W, fc1b, fc2W, fc2b, out);
}